// Round 1
// 12.968 us; speedup vs baseline: 1.0212x; 1.0212x over previous
//
#include <hip/hip_runtime.h>
#include <stdint.h>

// RoI max-pool: feature_map (C,H,W) f32, proposals (N,4) f32 -> out (N,C,7,7) f32
//
// One WAVE handles 8 channels of one proposal n.
//   - staging: global_load_lds width=16 (2 per channel). LDS dest is linear
//     lane*16B from a wave-uniform base; each buffer is 512 floats so BOTH
//     gll ops (128 float4 span) stay inside their own buffer.
//     Row pitch 24 floats = 6 float4 -> (row,quad) maps linearly to lane.
//     Tail lanes clamp their SOURCE row to rh-1 (duplicate data, never read).
//   - pipeline: FOUR channel buffers (NBUF=4). Prologue stages ch 0..3
//     (8 loads in flight); iteration k computes ch k from buf[k&3], stores,
//     then restages buf[k&3] for ch k+4. Restage is safe: ch k's ds_reads are
//     drained by the store's data dependency before the gll16 issues, and the
//     gll16's LDS write lands >=1 memory latency after issue.
//   - counted waits from the exact FIFO (8 prologue loads, then per-iter
//     {store, 2 loads}): vmcnt {6,7,8,9,9,7,5,3} for k=0..7. Never a drain.
//   - compute: extents wave-uniform f(rw,rh) (scalarized); uniform branch into
//     E^2-read clamped binmax, branch-free per lane.
// Fallback path (degenerate/oversized region) matches the reference exactly.

constexpr int Cc = 256, Hh = 56, Ww = 56, OUTS = 7;
constexpr int CHW = Hh * Ww;        // 3136
constexpr float SCALEF = 0.0625f;   // 1/16, exact in f32
constexpr float NEGF = -3.4e+38f;
constexpr int RH     = 20;          // max staged rows (this distro: rh<=19)
constexpr int RWQ    = 6;           // float4s per row (24-float window)
constexpr int PITCHF = 24;          // floats per LDS row (= RWQ*4, linear lane map)
constexpr int BUFF   = 512;         // floats per channel buffer (2 gll = 128x16B)
constexpr int WPB    = 4;           // waves per block
constexpr int CPW    = 8;           // channels per wave
constexpr int NBUF   = 4;           // pipeline depth (channel buffers per wave)

__device__ __forceinline__ void gll16(const float* g, float* l) {
    __builtin_amdgcn_global_load_lds(
        (const __attribute__((address_space(1))) uint32_t*)g,
        (__attribute__((address_space(3))) uint32_t*)l, 16, 0, 0);
}

template <int E>
__device__ __forceinline__ float binmax(const float* __restrict__ base,
                                        int eh, int ew)
{
    // base = &buf[hs*PITCHF + wofs + ws]; clamped duplicates stay inside the bin
    float m = NEGF;
#pragma unroll
    for (int kr = 0; kr < E; ++kr) {
        const int ro = min(kr, eh) * PITCHF;
#pragma unroll
        for (int kc = 0; kc < E; ++kc)
            m = fmaxf(m, base[ro + min(kc, ew)]);
    }
    return m;
}

__global__ __launch_bounds__(256) void roipool_kernel(
    const float* __restrict__ fm,      // (C,H,W)
    const float* __restrict__ props,   // (N,4)
    float* __restrict__ out)           // (N,C,7,7) flat
{
    __shared__ float lds[WPB][NBUF][BUFF];     // 32 KB/block

    const int lane = threadIdx.x & 63;
    const int wid  = __builtin_amdgcn_readfirstlane(threadIdx.x >> 6);
    const int n    = blockIdx.x >> 3;          // 8 channel-groups per n
    const int cg   = blockIdx.x & 7;
    const int c0   = cg * (WPB * CPW) + wid * CPW;

    // box (exact match to jnp.floor(p*0.0625) + clamps); wave-uniform -> SGPR
    const float4 p = reinterpret_cast<const float4*>(props)[n];
    const int x1 = __builtin_amdgcn_readfirstlane(max((int)floorf(p.x * SCALEF), 0));
    const int y1 = __builtin_amdgcn_readfirstlane(max((int)floorf(p.y * SCALEF), 0));
    const int x2 = __builtin_amdgcn_readfirstlane(min((int)floorf(p.z * SCALEF), Ww));
    const int y2 = __builtin_amdgcn_readfirstlane(min((int)floorf(p.w * SCALEF), Hh));
    const int rw = x2 - x1;
    const int rh = y2 - y1;

    float* dst0 = out + ((size_t)n * Cc + c0) * (OUTS * OUTS);
    const float* base0 = fm + (size_t)c0 * CHW;
    const int x1a = x1 & ~3;            // aligned window start

    // fast path: region fits 20x24 window; overread never passes end of fm
    if (rw > 0 && rh > 0 && rw <= 20 && rh <= RH &&
        (y1 + rh < Hh || x1a + RWQ * 4 <= Ww)) {

        // ---- wave-uniform max bin extent (scalar) ----
        int EW = 1, EH = 1;
#pragma unroll
        for (int i = 0; i < 7; ++i) {
            EW = max(EW, ((i + 1) * rw + 6) / 7 - (i * rw) / 7);
            EH = max(EH, ((i + 1) * rh + 6) / 7 - (i * rh) / 7);
        }
        const int E = max(EW, EH);      // in {1..4}

        // ---- per-lane staging source offsets (row-clamped: count-stable) ----
        const int r0 = lane / RWQ,        q0 = lane - r0 * RWQ;
        const int r1 = (lane + 64) / RWQ, q1 = (lane + 64) - r1 * RWQ;
        const int go0 = min(r0, rh - 1) * Ww + q0 * 4;
        const int go1 = min(r1, rh - 1) * Ww + q1 * 4;
        const float* src0 = base0 + y1 * Ww + x1a;    // 16B-aligned

        // ---- per-lane bin coords ----
        const int ow = lane % OUTS;
        const int oh = lane / OUTS;
        const int ws = (ow * rw) / OUTS;
        const int ew = ((ow + 1) * rw + 6) / OUTS - ws - 1;   // extent-1 >= 0
        const int hs = (oh * rh) / OUTS;
        const int eh = ((oh + 1) * rh + 6) / OUTS - hs - 1;
        const int bofs = hs * PITCHF + (x1 - x1a) + ws;

        // ---- prologue: stage channels 0..3 (8 loads in flight) ----
#pragma unroll
        for (int k = 0; k < NBUF; ++k) {
            const float* s = src0 + k * CHW;
            float* b = &lds[wid][k][0];
            gll16(s + go0, b);
            gll16(s + go1, b + 256);
        }
        __builtin_amdgcn_sched_barrier(0);

#pragma unroll
        for (int k = 0; k < CPW; ++k) {
            // counted waits: exactly drain channel k's 2 loads.
            // FIFO: L0L0 L1L1 L2L2 L3L3 | S0 L4L4 | S1 L5L5 | S2 L6L6 |
            //       S3 L7L7 | S4 | S5 | S6 | S7
            if      (k == 0) asm volatile("s_waitcnt vmcnt(6)" ::: "memory");
            else if (k == 1) asm volatile("s_waitcnt vmcnt(7)" ::: "memory");
            else if (k == 2) asm volatile("s_waitcnt vmcnt(8)" ::: "memory");
            else if (k == 3) asm volatile("s_waitcnt vmcnt(9)" ::: "memory");
            else if (k == 4) asm volatile("s_waitcnt vmcnt(9)" ::: "memory");
            else if (k == 5) asm volatile("s_waitcnt vmcnt(7)" ::: "memory");
            else if (k == 6) asm volatile("s_waitcnt vmcnt(5)" ::: "memory");
            else             asm volatile("s_waitcnt vmcnt(3)" ::: "memory");
            __builtin_amdgcn_sched_barrier(0);

            if (lane < OUTS * OUTS) {
                const float* bb = &lds[wid][k & (NBUF - 1)][0] + bofs;
                float m;
                if (E <= 2)      m = binmax<2>(bb, eh, ew);
                else if (E == 3) m = binmax<3>(bb, eh, ew);
                else             m = binmax<4>(bb, eh, ew);
                dst0[k * (OUTS * OUTS) + lane] = m;
            }
            // pin: restage must not be hoisted above the compute that reads
            // this buffer (HW-safe once order is pinned: ch k's ds_reads are
            // complete before the store issues; gll16's LDS write lands later)
            __builtin_amdgcn_sched_barrier(0);

            if (k + NBUF < CPW) {                    // restage buf[k&3] for k+4
                const float* s = src0 + (k + NBUF) * CHW;
                float* b = &lds[wid][k & (NBUF - 1)][0];
                gll16(s + go0, b);
                gll16(s + go1, b + 256);
                __builtin_amdgcn_sched_barrier(0);
            }
        }
    } else {
        // ---- general fallback (not hit by this input distribution) ----
        if (lane < OUTS * OUTS) {
            const int ow = lane % OUTS;
            const int oh = lane / OUTS;
            for (int k = 0; k < CPW; ++k) {
                float m = NEGF;
                if (rw > 0 && rh > 0) {
                    const int ws = x1 + (ow * rw) / OUTS;
                    const int we = min(x1 + ((ow + 1) * rw + 6) / OUTS, Ww);
                    const int hs = y1 + (oh * rh) / OUTS;
                    const int he = min(y1 + ((oh + 1) * rh + 6) / OUTS, Hh);
                    const float* b = base0 + (size_t)k * CHW;
                    for (int h = hs; h < he; ++h)
                        for (int w = ws; w < we; ++w)
                            m = fmaxf(m, b[h * Ww + w]);
                }
                dst0[k * (OUTS * OUTS) + lane] = m;
            }
        }
    }
}

extern "C" void kernel_launch(void* const* d_in, const int* in_sizes, int n_in,
                              void* d_out, int out_size, void* d_ws, size_t ws_size,
                              hipStream_t stream)
{
    const float* fm    = (const float*)d_in[0];   // (256,56,56)
    const float* props = (const float*)d_in[1];   // (128,4)
    float* out = (float*)d_out;                   // (128,256,7,7)

    const int N = in_sizes[1] / 4;                 // 128
    const int blocks = N * (Cc / (WPB * CPW));     // 1024 blocks x 256 threads
    roipool_kernel<<<blocks, 256, 0, stream>>>(fm, props, out);
}